// Round 2
// baseline (279.319 us; speedup 1.0000x reference)
//
#include <hip/hip_runtime.h>
#include <cstdint>
#include <climits>

#define BS 32
#define K 50000
#define NGT 32
#define KROW (K * 5)                 // 250000 floats per row of priors/loc_t
#define KEY_NEG1 0x407FFFFFu         // f2key(-1.0f)

// float -> order-preserving uint32 (ascending)
__device__ __forceinline__ unsigned f2key(float f) {
    unsigned b = __float_as_uint(f);
    return (b & 0x80000000u) ? ~b : (b | 0x80000000u);
}

// ---------------- Kernel A: match, loc_t, loss key, pos count, byte3 hist ----
__global__ __launch_bounds__(256) void kA(const float* __restrict__ conf,
                                          const float* __restrict__ gt,
                                          const float* __restrict__ priors,
                                          float* __restrict__ loc_t,
                                          unsigned* __restrict__ keys,
                                          unsigned* __restrict__ ghist,
                                          int* __restrict__ numpos) {
    const int b   = blockIdx.y;
    const int tid = threadIdx.x;
    const int k0  = blockIdx.x * 256;

    __shared__ float sp[1280];       // staged prior chunk (linear element order)
    __shared__ float so[1280];       // staged loc_t chunk
    __shared__ float gs[NGT * 5];
    __shared__ int   gv[NGT];
    __shared__ int   lh[256];
    __shared__ int   lpos;

    lh[tid] = 0;
    if (tid == 0) lpos = 0;
    if (tid < NGT * 5) gs[tid] = gt[b * NGT * 5 + tid];

    const int ebase = k0 * 5;
#pragma unroll
    for (int j = 0; j < 5; j++) {
        const int e = ebase + j * 256 + tid;
        if (e < KROW) sp[j * 256 + tid] = priors[(size_t)b * KROW + e];
    }
    __syncthreads();
    if (tid < NGT) {
        const float* g = &gs[tid * 5];
        gv[tid] = !(g[0] == 0.f && g[1] == 0.f && g[2] == 0.f &&
                    g[3] == 0.f && g[4] == 0.f);
    }
    __syncthreads();

    const int k = k0 + tid;
    if (k < K) {
        const float px = sp[tid * 5], py = sp[tid * 5 + 1], pw = sp[tid * 5 + 2],
                    ph = sp[tid * 5 + 3], pa = sp[tid * 5 + 4];
        float sx = 0.f, sy = 0.f, sw = 0.f, sh = 0.f, sa = 0.f;
        int cnt = 0;
#pragma unroll
        for (int n = 0; n < NGT; n++) {
            if (!gv[n]) continue;
            const float gx = gs[n * 5], gy = gs[n * 5 + 1], ga = gs[n * 5 + 4];
            if (fabsf(px - gx) <= 16.f && fabsf(py - gy) <= 16.f &&
                fabsf(pa - ga) <= 15.f) {
                cnt++;
                sx += gx; sy += gy; sw += gs[n * 5 + 2]; sh += gs[n * 5 + 3]; sa += ga;
            }
        }
        float lx = sx + 1e-14f, ly = sy + 1e-14f, lw = sw + 1e-14f,
              lh2 = sh + 1e-14f, la = sa + 1e-14f;
        if (cnt > 0) {
            const float c = (float)cnt;
            lx /= c; ly /= c; lw /= c; lh2 /= c; la /= c;
        }
        so[tid * 5]     = ((lx - px) / pw) / 0.1f;
        so[tid * 5 + 1] = ((ly - py) / ph) / 0.1f;
        so[tid * 5 + 2] = logf(lw / pw) / 0.2f;
        so[tid * 5 + 3] = logf(lh2 / ph) / 0.2f;
        so[tid * 5 + 4] = (la - pa) / 0.1f;

        const float2 c2 = ((const float2*)conf)[(size_t)b * K + k];
        const float m = fmaxf(c2.x, c2.y);
        const float lse = m + logf(expf(c2.x - m) + expf(c2.y - m));
        const float loss = (cnt > 0) ? -1.0f : (lse - c2.x);
        const unsigned key = f2key(loss);
        keys[(size_t)b * K + k] = key;
        atomicAdd(&lh[key >> 24], 1);
        if (cnt > 0) atomicAdd(&lpos, 1);
    }
    __syncthreads();
#pragma unroll
    for (int j = 0; j < 5; j++) {
        const int e = ebase + j * 256 + tid;
        if (e < KROW) loc_t[(size_t)b * KROW + e] = so[j * 256 + tid];
    }
    const int h = lh[tid];
    if (h) atomicAdd(&ghist[b * 256 + tid], (unsigned)h);
    if (tid == 0 && lpos) atomicAdd(&numpos[b], lpos);
}

// ------------- Kernel B: per-row radix select with compaction ----------------
__global__ __launch_bounds__(1024) void kB(const unsigned* __restrict__ keys,
                                           const unsigned* __restrict__ ghist,
                                           const int* __restrict__ numpos,
                                           unsigned* __restrict__ thresh,
                                           int* __restrict__ budget,
                                           unsigned* __restrict__ compact,
                                           unsigned* __restrict__ gcount,
                                           float* __restrict__ tie_region) {
    const int row = blockIdx.x;
    const int tid = threadIdx.x;
    const long long want0 = 3LL * (long long)numpos[row];
    if (want0 <= 0) {
        if (tid == 0) { thresh[row] = 0xFFFFFFFFu; budget[row] = 0; }
        return;
    }
    const int want_init = (want0 > K) ? K : (int)want0;

    __shared__ int hist[256];
    __shared__ unsigned s_b3, s_b2, s_b1, s_prefix;
    __shared__ int s_want, s_ceq, s_cand;

    // level 3 (top byte) from precomputed histogram — no key reads
    if (tid < 256) hist[tid] = (int)ghist[row * 256 + tid];
    __syncthreads();
    if (tid == 0) {
        int cum = 0, chosen = 0, ceq = 0;
        for (int bn = 255; bn >= 0; bn--) {
            const int h = hist[bn];
            if (cum + h >= want_init) { chosen = bn; ceq = h; break; }
            cum += h;
        }
        s_b3 = (unsigned)chosen; s_want = want_init - cum; s_ceq = ceq; s_cand = ceq;
    }
    __syncthreads();
    const unsigned b3 = s_b3;
    const unsigned* kr = keys + (size_t)row * K;
    unsigned* cp = compact + (size_t)row * K;

    // pass over all keys: byte2 hist among byte3-matches + compact them
    if (tid < 256) hist[tid] = 0;
    __syncthreads();
    for (int i = tid; i < K; i += 1024) {
        const unsigned kk = kr[i];
        if ((kk >> 24) == b3) {
            atomicAdd(&hist[(kk >> 16) & 255u], 1);
            const unsigned slot = atomicAdd(&gcount[row], 1u);
            cp[slot] = kk;
        }
    }
    __syncthreads();
    if (tid == 0) {
        const int w = s_want;
        int cum = 0, chosen = 0, ceq = 0;
        for (int bn = 255; bn >= 0; bn--) {
            const int h = hist[bn];
            if (cum + h >= w) { chosen = bn; ceq = h; break; }
            cum += h;
        }
        s_b2 = (unsigned)chosen; s_want = w - cum; s_ceq = ceq;
    }
    __syncthreads();
    const unsigned b2 = s_b2;
    const int cand = s_cand;

    // byte1 over compacted list
    if (tid < 256) hist[tid] = 0;
    __syncthreads();
    for (int i = tid; i < cand; i += 1024) {
        const unsigned kk = cp[i];
        if (((kk >> 16) & 255u) == b2) atomicAdd(&hist[(kk >> 8) & 255u], 1);
    }
    __syncthreads();
    if (tid == 0) {
        const int w = s_want;
        int cum = 0, chosen = 0, ceq = 0;
        for (int bn = 255; bn >= 0; bn--) {
            const int h = hist[bn];
            if (cum + h >= w) { chosen = bn; ceq = h; break; }
            cum += h;
        }
        s_b1 = (unsigned)chosen; s_want = w - cum; s_ceq = ceq;
    }
    __syncthreads();
    const unsigned b1 = s_b1;

    // byte0 over compacted list
    if (tid < 256) hist[tid] = 0;
    __syncthreads();
    for (int i = tid; i < cand; i += 1024) {
        const unsigned kk = cp[i];
        if (((kk >> 16) & 255u) == b2 && ((kk >> 8) & 255u) == b1)
            atomicAdd(&hist[kk & 255u], 1);
    }
    __syncthreads();
    if (tid == 0) {
        const int w = s_want;
        int cum = 0, chosen = 0, ceq = 0;
        for (int bn = 255; bn >= 0; bn--) {
            const int h = hist[bn];
            if (cum + h >= w) { chosen = bn; ceq = h; break; }
            cum += h;
        }
        s_prefix = (b3 << 24) | (b2 << 16) | (b1 << 8) | (unsigned)chosen;
        s_want = w - cum; s_ceq = ceq;
    }
    __syncthreads();

    const unsigned uT = s_prefix;
    const int bud = s_want, ceq = s_ceq;
    if (tid == 0) {
        thresh[row] = uT;
        budget[row] = (bud >= ceq) ? INT_MAX : bud;
    }
    if (bud >= ceq) return;

    // Rare path: duplicated threshold value — rank ties in index order.
    __shared__ int wsum[16];
    __shared__ int s_run;
    if (tid == 0) s_run = 0;
    __syncthreads();
    int* tiei = (int*)tie_region;
    for (int base = 0; base < K; base += 1024) {
        const int i = base + tid;
        const bool eq = (i < K) && (kr[i] == uT);
        const unsigned long long bal = __ballot(eq);
        const int lane = tid & 63, wid = tid >> 6;
        if (lane == 0) wsum[wid] = __popcll(bal);
        __syncthreads();
        if (tid == 0) {
            int acc = s_run;
            for (int w = 0; w < 16; w++) { const int t = wsum[w]; wsum[w] = acc; acc += t; }
            s_run = acc;
        }
        __syncthreads();
        if (eq) {
            const int rank = wsum[wid] + __popcll(bal & ((1ull << lane) - 1ull));
            tiei[(size_t)row * K + i] = rank;
        }
        __syncthreads();
    }
}

// ---------------- Kernel D1: conf_t, vectorized ------------------------------
__global__ __launch_bounds__(256) void kD1(const uint4* __restrict__ keys4,
                                           const unsigned* __restrict__ thresh,
                                           const int* __restrict__ budget,
                                           float4* __restrict__ confout4) {
    const int t = blockIdx.x * 256 + threadIdx.x;
    if (t >= (BS * K) / 4) return;
    const int row = (t * 4) / K;          // K%4==0 -> uniform within vec
    const unsigned uT = thresh[row];
    const int bud = budget[row];
    const uint4 kv = keys4[t];
    const int* tie = (const int*)confout4;
    float r[4];
    const unsigned ka[4] = {kv.x, kv.y, kv.z, kv.w};
#pragma unroll
    for (int j = 0; j < 4; j++) {
        const unsigned key = ka[j];
        const bool pos = (key == KEY_NEG1);
        bool sel;
        if (key > uT) sel = true;
        else if (key == uT) sel = (bud == INT_MAX) || (tie[t * 4 + j] < bud);
        else sel = false;
        r[j] = pos ? 1.0f : ((sel && !pos) ? 0.0f : -1.0f);
    }
    confout4[t] = make_float4(r[0], r[1], r[2], r[3]);
}

// ---------------- Kernel D2: iw / ow, float4 stores --------------------------
__global__ __launch_bounds__(256) void kD2(const float* __restrict__ confv,
                                           const int* __restrict__ numpos,
                                           float4* __restrict__ iw4,
                                           float4* __restrict__ ow4) {
    const int t = blockIdx.x * 256 + threadIdx.x;
    if (t >= (BS * K * 5) / 4) return;
    const int e0 = t * 4;
    const int row = e0 / KROW;            // KROW%4==0 -> uniform within vec
    const float inv = 1.0f / (float)((numpos[row] * 4) | 1);
    float iwv[4], owv[4];
#pragma unroll
    for (int j = 0; j < 4; j++) {
        const int p = (e0 + j) / 5;       // global prior index
        const float c = confv[p];
        iwv[j] = (c == 1.0f) ? 1.0f : 0.0f;
        owv[j] = (c >= 0.0f) ? inv : 0.0f;
    }
    iw4[t] = make_float4(iwv[0], iwv[1], iwv[2], iwv[3]);
    ow4[t] = make_float4(owv[0], owv[1], owv[2], owv[3]);
}

extern "C" void kernel_launch(void* const* d_in, const int* in_sizes, int n_in,
                              void* d_out, int out_size, void* d_ws, size_t ws_size,
                              hipStream_t stream) {
    const float* conf   = (const float*)d_in[0];  // [32,50000,2]
    const float* gt     = (const float*)d_in[1];  // [32,32,5]
    const float* priors = (const float*)d_in[2];  // [32,50000,5]

    float* out   = (float*)d_out;
    float* loc_t = out;                 // 8,000,000
    float* confo = out + 8000000;       // 1,600,000
    float* iw    = out + 9600000;       // 8,000,000
    float* ow    = out + 17600000;      // 8,000,000

    // Scratch inside ow region (fully rewritten by kD2 at the very end):
    unsigned* owu     = (unsigned*)ow;
    unsigned* keys    = owu;                       // [0, 1.6M)
    unsigned* ghist   = owu + 1600000;             // [1.6M, +8192)
    unsigned* gcount  = owu + 1608192;             // 32
    unsigned* compact = owu + 1608224;             // 32 rows x K worst case
    // Small per-row scalars in d_ws (>= 384 B proven in round 0):
    int*      numpos  = (int*)d_ws;                // 32
    unsigned* thresh  = (unsigned*)d_ws + 32;      // 32
    int*      budget  = (int*)d_ws + 64;           // 32

    hipMemsetAsync(d_ws, 0, 3 * 32 * sizeof(int), stream);
    hipMemsetAsync(ghist, 0, (8192 + 32) * sizeof(unsigned), stream);

    dim3 gA((K + 255) / 256, BS);
    kA<<<gA, 256, 0, stream>>>(conf, gt, priors, loc_t, keys, ghist, numpos);
    kB<<<BS, 1024, 0, stream>>>(keys, ghist, numpos, thresh, budget,
                                compact, gcount, confo);
    kD1<<<((BS * K) / 4 + 255) / 256, 256, 0, stream>>>((const uint4*)keys,
                                                        thresh, budget,
                                                        (float4*)confo);
    kD2<<<((BS * K * 5) / 4 + 255) / 256, 256, 0, stream>>>(confo, numpos,
                                                            (float4*)iw,
                                                            (float4*)ow);
}

// Round 3
// 125.294 us; speedup vs baseline: 2.2293x; 2.2293x over previous
//
#include <hip/hip_runtime.h>
#include <cstdint>
#include <climits>

#define BS 32
#define K 50000
#define K4 12500                 // K/4 uint4 per row
#define NCH 49                   // ceil(K/1024) chunks per row
#define NGT 32
#define KROW (K * 5)
#define KEY_NEG1 0x407FFFFFu     // f2key(-1.0f)

__device__ __forceinline__ unsigned f2key(float f) {
    unsigned b = __float_as_uint(f);
    return (b & 0x80000000u) ? ~b : (b | 0x80000000u);
}

struct Sel { int bin; int want; int ceq; };

// Block-parallel (256 threads): pick highest bin with inclusive-from-top
// cumulative >= want. T = LDS int[256] scratch, r = LDS result.
__device__ __forceinline__ void pick256(const unsigned* __restrict__ hist_row,
                                        int want, int tid, int* T, Sel* r) {
    const int h = (int)hist_row[tid];
    T[tid] = h;
    __syncthreads();
#pragma unroll
    for (int o = 1; o < 256; o <<= 1) {          // suffix inclusive sum
        const int add = (tid + o < 256) ? T[tid + o] : 0;
        __syncthreads();
        T[tid] += add;
        __syncthreads();
    }
    const int Ti = T[tid];
    const int Tn = (tid == 255) ? (want - 1) : T[tid + 1];
    if (Ti >= want && Tn < want) { r->bin = tid; r->ceq = h; r->want = want - (Ti - h); }
    __syncthreads();
}

__device__ __forceinline__ int want_of(int np) {
    const long long w0 = 3LL * (long long)np;
    return (w0 > K) ? K : (int)w0;
}

// ---------------- Kernel A: match, loc_t, loss key, pos count, byte3 hist ----
__global__ __launch_bounds__(256) void kA(const float* __restrict__ conf,
                                          const float* __restrict__ gt,
                                          const float* __restrict__ priors,
                                          float* __restrict__ loc_t,
                                          unsigned* __restrict__ keys,
                                          unsigned* __restrict__ ghist,
                                          int* __restrict__ numpos) {
    const int b   = blockIdx.y;
    const int tid = threadIdx.x;
    const int k0  = blockIdx.x * 256;

    __shared__ float sp[1280];
    __shared__ float so[1280];
    __shared__ float gs[NGT * 5];
    __shared__ int   gv[NGT];
    __shared__ int   lh[256];
    __shared__ int   lpos;

    lh[tid] = 0;
    if (tid == 0) lpos = 0;
    if (tid < NGT * 5) gs[tid] = gt[b * NGT * 5 + tid];

    const int ebase = k0 * 5;
#pragma unroll
    for (int j = 0; j < 5; j++) {
        const int e = ebase + j * 256 + tid;
        if (e < KROW) sp[j * 256 + tid] = priors[(size_t)b * KROW + e];
    }
    __syncthreads();
    if (tid < NGT) {
        const float* g = &gs[tid * 5];
        gv[tid] = !(g[0] == 0.f && g[1] == 0.f && g[2] == 0.f &&
                    g[3] == 0.f && g[4] == 0.f);
    }
    __syncthreads();

    const int k = k0 + tid;
    if (k < K) {
        const float px = sp[tid * 5], py = sp[tid * 5 + 1], pw = sp[tid * 5 + 2],
                    ph = sp[tid * 5 + 3], pa = sp[tid * 5 + 4];
        float sx = 0.f, sy = 0.f, sw = 0.f, sh = 0.f, sa = 0.f;
        int cnt = 0;
#pragma unroll
        for (int n = 0; n < NGT; n++) {
            if (!gv[n]) continue;
            const float gx = gs[n * 5], gy = gs[n * 5 + 1], ga = gs[n * 5 + 4];
            if (fabsf(px - gx) <= 16.f && fabsf(py - gy) <= 16.f &&
                fabsf(pa - ga) <= 15.f) {
                cnt++;
                sx += gx; sy += gy; sw += gs[n * 5 + 2]; sh += gs[n * 5 + 3]; sa += ga;
            }
        }
        float lx = sx + 1e-14f, ly = sy + 1e-14f, lw = sw + 1e-14f,
              lh2 = sh + 1e-14f, la = sa + 1e-14f;
        if (cnt > 0) {
            const float c = (float)cnt;
            lx /= c; ly /= c; lw /= c; lh2 /= c; la /= c;
        }
        so[tid * 5]     = ((lx - px) / pw) / 0.1f;
        so[tid * 5 + 1] = ((ly - py) / ph) / 0.1f;
        so[tid * 5 + 2] = logf(lw / pw) / 0.2f;
        so[tid * 5 + 3] = logf(lh2 / ph) / 0.2f;
        so[tid * 5 + 4] = (la - pa) / 0.1f;

        const float2 c2 = ((const float2*)conf)[(size_t)b * K + k];
        const float m = fmaxf(c2.x, c2.y);
        const float lse = m + logf(expf(c2.x - m) + expf(c2.y - m));
        const float loss = (cnt > 0) ? -1.0f : (lse - c2.x);
        const unsigned key = f2key(loss);
        keys[(size_t)b * K + k] = key;
        atomicAdd(&lh[key >> 24], 1);
        if (cnt > 0) atomicAdd(&lpos, 1);
    }
    __syncthreads();
#pragma unroll
    for (int j = 0; j < 5; j++) {
        const int e = ebase + j * 256 + tid;
        if (e < KROW) loc_t[(size_t)b * KROW + e] = so[j * 256 + tid];
    }
    const int h = lh[tid];
    if (h) atomicAdd(&ghist[b * 256 + tid], (unsigned)h);
    if (tid == 0 && lpos) atomicAdd(&numpos[b], lpos);
}

// ---------------- H2: byte2 histogram among byte3-matching keys --------------
__global__ __launch_bounds__(256) void kH2(const unsigned* __restrict__ keys,
                                           const unsigned* __restrict__ ghist,
                                           const int* __restrict__ numpos,
                                           unsigned* __restrict__ hist2) {
    const int row = blockIdx.y, tid = threadIdx.x;
    const int np = numpos[row];
    if (np <= 0) return;
    __shared__ int T[256];
    __shared__ Sel r;
    __shared__ int lh[256];
    pick256(ghist + row * 256, want_of(np), tid, T, &r);
    const int b3 = r.bin;
    lh[tid] = 0;
    __syncthreads();
    const int i4 = blockIdx.x * 256 + tid;
    if (i4 < K4) {
        const uint4 kv = ((const uint4*)(keys + (size_t)row * K))[i4];
        const unsigned ka[4] = {kv.x, kv.y, kv.z, kv.w};
#pragma unroll
        for (int j = 0; j < 4; j++)
            if ((int)(ka[j] >> 24) == b3) atomicAdd(&lh[(ka[j] >> 16) & 255u], 1);
    }
    __syncthreads();
    if (lh[tid]) atomicAdd(&hist2[row * 256 + tid], (unsigned)lh[tid]);
}

// ---------------- H1: byte1 histogram among prefix16-matching keys -----------
__global__ __launch_bounds__(256) void kH1(const unsigned* __restrict__ keys,
                                           const unsigned* __restrict__ ghist,
                                           const unsigned* __restrict__ hist2,
                                           const int* __restrict__ numpos,
                                           unsigned* __restrict__ hist1) {
    const int row = blockIdx.y, tid = threadIdx.x;
    const int np = numpos[row];
    if (np <= 0) return;
    __shared__ int T[256];
    __shared__ Sel r;
    __shared__ int lh[256];
    pick256(ghist + row * 256, want_of(np), tid, T, &r);
    const unsigned b3 = (unsigned)r.bin;
    pick256(hist2 + row * 256, r.want, tid, T, &r);
    const unsigned p16 = (b3 << 8) | (unsigned)r.bin;
    lh[tid] = 0;
    __syncthreads();
    const int i4 = blockIdx.x * 256 + tid;
    if (i4 < K4) {
        const uint4 kv = ((const uint4*)(keys + (size_t)row * K))[i4];
        const unsigned ka[4] = {kv.x, kv.y, kv.z, kv.w};
#pragma unroll
        for (int j = 0; j < 4; j++)
            if ((ka[j] >> 16) == p16) atomicAdd(&lh[(ka[j] >> 8) & 255u], 1);
    }
    __syncthreads();
    if (lh[tid]) atomicAdd(&hist1[row * 256 + tid], (unsigned)lh[tid]);
}

// ---------------- H0: byte0 histogram among prefix24-matching keys -----------
__global__ __launch_bounds__(256) void kH0(const unsigned* __restrict__ keys,
                                           const unsigned* __restrict__ ghist,
                                           const unsigned* __restrict__ hist2,
                                           const unsigned* __restrict__ hist1,
                                           const int* __restrict__ numpos,
                                           unsigned* __restrict__ hist0) {
    const int row = blockIdx.y, tid = threadIdx.x;
    const int np = numpos[row];
    if (np <= 0) return;
    __shared__ int T[256];
    __shared__ Sel r;
    __shared__ int lh[256];
    pick256(ghist + row * 256, want_of(np), tid, T, &r);
    unsigned pfx = (unsigned)r.bin;
    pick256(hist2 + row * 256, r.want, tid, T, &r);
    pfx = (pfx << 8) | (unsigned)r.bin;
    pick256(hist1 + row * 256, r.want, tid, T, &r);
    pfx = (pfx << 8) | (unsigned)r.bin;              // 24-bit prefix
    lh[tid] = 0;
    __syncthreads();
    const int i4 = blockIdx.x * 256 + tid;
    if (i4 < K4) {
        const uint4 kv = ((const uint4*)(keys + (size_t)row * K))[i4];
        const unsigned ka[4] = {kv.x, kv.y, kv.z, kv.w};
#pragma unroll
        for (int j = 0; j < 4; j++)
            if ((ka[j] >> 8) == pfx) atomicAdd(&lh[ka[j] & 255u], 1);
    }
    __syncthreads();
    if (lh[tid]) atomicAdd(&hist0[row * 256 + tid], (unsigned)lh[tid]);
}

// ---------------- F: finalize thresh/budget/tieflag per row ------------------
__global__ __launch_bounds__(256) void kF(const unsigned* __restrict__ ghist,
                                          const unsigned* __restrict__ hist2,
                                          const unsigned* __restrict__ hist1,
                                          const unsigned* __restrict__ hist0,
                                          const int* __restrict__ numpos,
                                          unsigned* __restrict__ thresh,
                                          int* __restrict__ budget,
                                          unsigned* __restrict__ tieflag) {
    const int row = blockIdx.x, tid = threadIdx.x;
    const int np = numpos[row];
    if (np <= 0) {
        if (tid == 0) { thresh[row] = 0xFFFFFFFFu; budget[row] = 0; tieflag[row] = 0; }
        return;
    }
    __shared__ int T[256];
    __shared__ Sel r;
    pick256(ghist + row * 256, want_of(np), tid, T, &r);
    unsigned pfx = (unsigned)r.bin;
    pick256(hist2 + row * 256, r.want, tid, T, &r);
    pfx = (pfx << 8) | (unsigned)r.bin;
    pick256(hist1 + row * 256, r.want, tid, T, &r);
    pfx = (pfx << 8) | (unsigned)r.bin;
    pick256(hist0 + row * 256, r.want, tid, T, &r);
    pfx = (pfx << 8) | (unsigned)r.bin;
    if (tid == 0) {
        thresh[row] = pfx;
        const bool tie = (r.want < r.ceq);
        budget[row] = tie ? r.want : INT_MAX;
        tieflag[row] = tie ? 1u : 0u;
    }
}

// ---------------- Ta/Tb/Tc: tie ranking (rare, early-out) --------------------
__global__ __launch_bounds__(256) void kTa(const unsigned* __restrict__ keys,
                                           const unsigned* __restrict__ thresh,
                                           const unsigned* __restrict__ tieflag,
                                           int* __restrict__ chunkcnt) {
    const int row = blockIdx.y, tid = threadIdx.x;
    if (!tieflag[row]) return;
    const unsigned uT = thresh[row];
    int c = 0;
    const int i4 = blockIdx.x * 256 + tid;
    if (i4 < K4) {
        const uint4 kv = ((const uint4*)(keys + (size_t)row * K))[i4];
        c = (kv.x == uT) + (kv.y == uT) + (kv.z == uT) + (kv.w == uT);
    }
    __shared__ int s[256];
    s[tid] = c;
    __syncthreads();
#pragma unroll
    for (int o = 128; o; o >>= 1) { if (tid < o) s[tid] += s[tid + o]; __syncthreads(); }
    if (tid == 0) chunkcnt[row * NCH + blockIdx.x] = s[0];
}

__global__ __launch_bounds__(64) void kTb(const unsigned* __restrict__ tieflag,
                                          const int* __restrict__ chunkcnt,
                                          int* __restrict__ chunkoff) {
    const int row = blockIdx.x;
    if (!tieflag[row] || threadIdx.x != 0) return;
    int run = 0;
    for (int c = 0; c < NCH; c++) {
        const int t = chunkcnt[row * NCH + c];
        chunkoff[row * NCH + c] = run;
        run += t;
    }
}

__global__ __launch_bounds__(256) void kTc(const unsigned* __restrict__ keys,
                                           const unsigned* __restrict__ thresh,
                                           const unsigned* __restrict__ tieflag,
                                           const int* __restrict__ chunkoff,
                                           int* __restrict__ tie) {
    const int row = blockIdx.y, tid = threadIdx.x;
    if (!tieflag[row]) return;
    const unsigned uT = thresh[row];
    const int i4 = blockIdx.x * 256 + tid;
    unsigned m = 0;
    if (i4 < K4) {
        const uint4 kv = ((const uint4*)(keys + (size_t)row * K))[i4];
        m = (kv.x == uT) | ((kv.y == uT) << 1) | ((kv.z == uT) << 2) | ((kv.w == uT) << 3);
    }
    const int cnt = __popc(m);
    __shared__ int S[256];
    S[tid] = cnt;
    __syncthreads();
#pragma unroll
    for (int o = 1; o < 256; o <<= 1) {      // inclusive scan (thread order)
        const int a = (tid >= o) ? S[tid - o] : 0;
        __syncthreads();
        S[tid] += a;
        __syncthreads();
    }
    int rank = chunkoff[row * NCH + blockIdx.x] + S[tid] - cnt;
#pragma unroll
    for (int j = 0; j < 4; j++) {
        if (m & (1u << j)) { tie[(size_t)row * K + i4 * 4 + j] = rank; rank++; }
    }
}

// ---------------- D1: conf_t -------------------------------------------------
__global__ __launch_bounds__(256) void kD1(const uint4* __restrict__ keys4,
                                           const unsigned* __restrict__ thresh,
                                           const int* __restrict__ budget,
                                           float4* __restrict__ confout4) {
    const int t = blockIdx.x * 256 + threadIdx.x;
    if (t >= (BS * K) / 4) return;
    const int row = (t * 4) / K;
    const unsigned uT = thresh[row];
    const int bud = budget[row];
    const uint4 kv = keys4[t];
    const int* tie = (const int*)confout4;
    float rr[4];
    const unsigned ka[4] = {kv.x, kv.y, kv.z, kv.w};
#pragma unroll
    for (int j = 0; j < 4; j++) {
        const unsigned key = ka[j];
        const bool pos = (key == KEY_NEG1);
        bool sel;
        if (key > uT) sel = true;
        else if (key == uT)
            sel = (bud == INT_MAX) || (bud > 0 && tie[t * 4 + j] < bud);
        else sel = false;
        rr[j] = pos ? 1.0f : ((sel && !pos) ? 0.0f : -1.0f);
    }
    confout4[t] = make_float4(rr[0], rr[1], rr[2], rr[3]);
}

// ---------------- D2: iw / ow ------------------------------------------------
__global__ __launch_bounds__(256) void kD2(const float* __restrict__ confv,
                                           const int* __restrict__ numpos,
                                           float4* __restrict__ iw4,
                                           float4* __restrict__ ow4) {
    const int t = blockIdx.x * 256 + threadIdx.x;
    if (t >= (BS * K * 5) / 4) return;
    const int e0 = t * 4;
    const int row = e0 / KROW;
    const float inv = 1.0f / (float)((numpos[row] * 4) | 1);
    float iwv[4], owv[4];
#pragma unroll
    for (int j = 0; j < 4; j++) {
        const float c = confv[(e0 + j) / 5];
        iwv[j] = (c == 1.0f) ? 1.0f : 0.0f;
        owv[j] = (c >= 0.0f) ? inv : 0.0f;
    }
    iw4[t] = make_float4(iwv[0], iwv[1], iwv[2], iwv[3]);
    ow4[t] = make_float4(owv[0], owv[1], owv[2], owv[3]);
}

extern "C" void kernel_launch(void* const* d_in, const int* in_sizes, int n_in,
                              void* d_out, int out_size, void* d_ws, size_t ws_size,
                              hipStream_t stream) {
    const float* conf   = (const float*)d_in[0];
    const float* gt     = (const float*)d_in[1];
    const float* priors = (const float*)d_in[2];

    float* out   = (float*)d_out;
    float* loc_t = out;
    float* confo = out + 8000000;
    float* iw    = out + 9600000;
    float* ow    = out + 17600000;

    // Scratch inside ow region (fully rewritten by kD2 last):
    unsigned* owu      = (unsigned*)ow;
    unsigned* keys     = owu;                        // 1,600,000
    unsigned* ghist    = owu + 1600000;              // 8192
    unsigned* hist2    = owu + 1608192;              // 8192
    unsigned* hist1    = owu + 1616384;              // 8192
    unsigned* hist0    = owu + 1624576;              // 8192
    int*      chunkcnt = (int*)(owu + 1632768);      // 32*49
    int*      chunkoff = (int*)(owu + 1634336);      // 32*49
    unsigned* tieflag  = owu + 1635904;              // 32
    int*      numpos   = (int*)d_ws;                 // 32
    unsigned* thresh   = (unsigned*)d_ws + 32;       // 32
    int*      budget   = (int*)d_ws + 64;            // 32

    hipMemsetAsync(d_ws, 0, 3 * 32 * sizeof(int), stream);
    hipMemsetAsync(ghist, 0, (1635936 - 1600000) * sizeof(unsigned), stream);

    dim3 gA((K + 255) / 256, BS);
    dim3 gP(NCH, BS);
    kA<<<gA, 256, 0, stream>>>(conf, gt, priors, loc_t, keys, ghist, numpos);
    kH2<<<gP, 256, 0, stream>>>(keys, ghist, numpos, hist2);
    kH1<<<gP, 256, 0, stream>>>(keys, ghist, hist2, numpos, hist1);
    kH0<<<gP, 256, 0, stream>>>(keys, ghist, hist2, hist1, numpos, hist0);
    kF<<<BS, 256, 0, stream>>>(ghist, hist2, hist1, hist0, numpos,
                               thresh, budget, tieflag);
    kTa<<<gP, 256, 0, stream>>>(keys, thresh, tieflag, chunkcnt);
    kTb<<<BS, 64, 0, stream>>>(tieflag, chunkcnt, chunkoff);
    kTc<<<gP, 256, 0, stream>>>(keys, thresh, tieflag, chunkoff, (int*)confo);
    kD1<<<((BS * K) / 4 + 255) / 256, 256, 0, stream>>>((const uint4*)keys,
                                                        thresh, budget,
                                                        (float4*)confo);
    kD2<<<((BS * K * 5) / 4 + 255) / 256, 256, 0, stream>>>(confo, numpos,
                                                            (float4*)iw,
                                                            (float4*)ow);
}

// Round 4
// 123.680 us; speedup vs baseline: 2.2584x; 1.0130x over previous
//
#include <hip/hip_runtime.h>
#include <cstdint>
#include <climits>

#define BS 32
#define K 50000
#define K4 12500                 // K/4 uint4 per row
#define NCH 49                   // ceil(K/1024)
#define NGT 32
#define KROW (K * 5)
#define KEY_NEG1 0x407FFFFFu     // f2key(-1.0f)

__device__ __forceinline__ unsigned f2key(float f) {
    unsigned b = __float_as_uint(f);
    return (b & 0x80000000u) ? ~b : (b | 0x80000000u);
}

struct Sel { int bin; int want; int ceq; };

// Block-parallel pick: highest bin with from-top cumulative >= want.
// Works for blockDim >= 256 (threads >= 256 idle through barriers).
__device__ __forceinline__ void pick256(const unsigned* __restrict__ hist_row,
                                        int want, int tid, int* T, Sel* r) {
    int h = 0;
    if (tid < 256) { h = (int)hist_row[tid]; T[tid] = h; }
    __syncthreads();
#pragma unroll
    for (int o = 1; o < 256; o <<= 1) {          // suffix inclusive sum
        int add = 0;
        if (tid < 256) add = (tid + o < 256) ? T[tid + o] : 0;
        __syncthreads();
        if (tid < 256) T[tid] += add;
        __syncthreads();
    }
    if (tid < 256) {
        const int Ti = T[tid];
        const int Tn = (tid == 255) ? (want - 1) : T[tid + 1];
        if (Ti >= want && Tn < want) { r->bin = tid; r->ceq = h; r->want = want - (Ti - h); }
    }
    __syncthreads();
}

__device__ __forceinline__ int want_of(int np) {
    const long long w0 = 3LL * (long long)np;
    return (w0 > K) ? K : (int)w0;
}

// ---------------- Kernel A: match, loc_t, loss key, pos count, byte3 hist ----
__global__ __launch_bounds__(256) void kA(const float* __restrict__ conf,
                                          const float* __restrict__ gt,
                                          const float* __restrict__ priors,
                                          float* __restrict__ loc_t,
                                          unsigned* __restrict__ keys,
                                          unsigned* __restrict__ ghist,
                                          int* __restrict__ numpos) {
    const int b   = blockIdx.y;
    const int tid = threadIdx.x;
    const int k0  = blockIdx.x * 256;
    const int lane = tid & 63;

    __shared__ float sp[1280];
    __shared__ float so[1280];
    __shared__ int   lh[256];
    __shared__ int   lpos;

    lh[tid] = 0;
    if (tid == 0) lpos = 0;

    const int ebase = k0 * 5;
#pragma unroll
    for (int j = 0; j < 5; j++) {
        const int e = ebase + j * 256 + tid;
        if (e < KROW) sp[j * 256 + tid] = priors[(size_t)b * KROW + e];
    }
    __syncthreads();

    const int k = k0 + tid;
    const bool valid_k = (k < K);
    unsigned key = 0;
    int cnt = 0;
    if (valid_k) {
        const float px = sp[tid * 5], py = sp[tid * 5 + 1], pw = sp[tid * 5 + 2],
                    ph = sp[tid * 5 + 3], pa = sp[tid * 5 + 4];
        // gt row via wave-uniform (scalar) loads — no LDS in the match loop
        const unsigned* gtu = (const unsigned*)(gt + (size_t)b * NGT * 5);
        float sx = 0.f, sy = 0.f, sw = 0.f, sh = 0.f, sa = 0.f;
#pragma unroll
        for (int n = 0; n < NGT; n++) {
            const unsigned ux = gtu[n * 5],     uy = gtu[n * 5 + 1],
                           uw = gtu[n * 5 + 2], uh = gtu[n * 5 + 3],
                           ua = gtu[n * 5 + 4];
            if ((ux | uy | uw | uh | ua) == 0u) continue;   // padding row (uniform)
            const float gx = __uint_as_float(ux), gy = __uint_as_float(uy),
                        ga = __uint_as_float(ua);
            if (fabsf(px - gx) <= 16.f && fabsf(py - gy) <= 16.f &&
                fabsf(pa - ga) <= 15.f) {
                cnt++;
                sx += gx; sy += gy; sw += __uint_as_float(uw);
                sh += __uint_as_float(uh); sa += ga;
            }
        }
        float lx = sx + 1e-14f, ly = sy + 1e-14f, lw = sw + 1e-14f,
              lh2 = sh + 1e-14f, la = sa + 1e-14f;
        if (cnt > 0) {
            const float c = (float)cnt;
            lx /= c; ly /= c; lw /= c; lh2 /= c; la /= c;
        }
        so[tid * 5]     = ((lx - px) / pw) / 0.1f;
        so[tid * 5 + 1] = ((ly - py) / ph) / 0.1f;
        so[tid * 5 + 2] = logf(lw / pw) / 0.2f;
        so[tid * 5 + 3] = logf(lh2 / ph) / 0.2f;
        so[tid * 5 + 4] = (la - pa) / 0.1f;

        const float2 c2 = ((const float2*)conf)[(size_t)b * K + k];
        const float m = fmaxf(c2.x, c2.y);
        const float lse = m + logf(expf(c2.x - m) + expf(c2.y - m));
        const float loss = (cnt > 0) ? -1.0f : (lse - c2.x);
        key = f2key(loss);
        keys[(size_t)b * K + k] = key;
    }

    // wave-aggregated histogram update (few distinct bins per wave)
    {
        const unsigned bin = key >> 24;
        bool todo = valid_k;
        while (__any(todo)) {
            const unsigned long long act = __ballot(todo);
            const int leader = __ffsll(act) - 1;
            const unsigned lbin = __shfl(bin, leader);
            const bool mine = todo && (bin == lbin);
            const unsigned long long grp = __ballot(mine);
            if (lane == leader) atomicAdd(&lh[lbin], (int)__popcll(grp));
            todo = todo && !mine;
        }
        const unsigned long long pm = __ballot(valid_k && cnt > 0);
        if (lane == 0 && pm) atomicAdd(&lpos, (int)__popcll(pm));
    }
    __syncthreads();
#pragma unroll
    for (int j = 0; j < 5; j++) {
        const int e = ebase + j * 256 + tid;
        if (e < KROW) loc_t[(size_t)b * KROW + e] = so[j * 256 + tid];
    }
    const int h = lh[tid];
    if (h) atomicAdd(&ghist[b * 256 + tid], (unsigned)h);
    if (tid == 0 && lpos) atomicAdd(&numpos[b], lpos);
}

// ---------------- H2/H1/H0: conditioned byte histograms ----------------------
__global__ __launch_bounds__(256) void kH2(const unsigned* __restrict__ keys,
                                           const unsigned* __restrict__ ghist,
                                           const int* __restrict__ numpos,
                                           unsigned* __restrict__ hist2) {
    const int row = blockIdx.y, tid = threadIdx.x;
    const int np = numpos[row];
    if (np <= 0) return;
    __shared__ int T[256];
    __shared__ Sel r;
    __shared__ int lh[256];
    pick256(ghist + row * 256, want_of(np), tid, T, &r);
    const int b3 = r.bin;
    lh[tid] = 0;
    __syncthreads();
    const int i4 = blockIdx.x * 256 + tid;
    if (i4 < K4) {
        const uint4 kv = ((const uint4*)(keys + (size_t)row * K))[i4];
        const unsigned ka[4] = {kv.x, kv.y, kv.z, kv.w};
#pragma unroll
        for (int j = 0; j < 4; j++)
            if ((int)(ka[j] >> 24) == b3) atomicAdd(&lh[(ka[j] >> 16) & 255u], 1);
    }
    __syncthreads();
    if (lh[tid]) atomicAdd(&hist2[row * 256 + tid], (unsigned)lh[tid]);
}

__global__ __launch_bounds__(256) void kH1(const unsigned* __restrict__ keys,
                                           const unsigned* __restrict__ ghist,
                                           const unsigned* __restrict__ hist2,
                                           const int* __restrict__ numpos,
                                           unsigned* __restrict__ hist1) {
    const int row = blockIdx.y, tid = threadIdx.x;
    const int np = numpos[row];
    if (np <= 0) return;
    __shared__ int T[256];
    __shared__ Sel r;
    __shared__ int lh[256];
    pick256(ghist + row * 256, want_of(np), tid, T, &r);
    const unsigned b3 = (unsigned)r.bin;
    pick256(hist2 + row * 256, r.want, tid, T, &r);
    const unsigned p16 = (b3 << 8) | (unsigned)r.bin;
    lh[tid] = 0;
    __syncthreads();
    const int i4 = blockIdx.x * 256 + tid;
    if (i4 < K4) {
        const uint4 kv = ((const uint4*)(keys + (size_t)row * K))[i4];
        const unsigned ka[4] = {kv.x, kv.y, kv.z, kv.w};
#pragma unroll
        for (int j = 0; j < 4; j++)
            if ((ka[j] >> 16) == p16) atomicAdd(&lh[(ka[j] >> 8) & 255u], 1);
    }
    __syncthreads();
    if (lh[tid]) atomicAdd(&hist1[row * 256 + tid], (unsigned)lh[tid]);
}

__global__ __launch_bounds__(256) void kH0(const unsigned* __restrict__ keys,
                                           const unsigned* __restrict__ ghist,
                                           const unsigned* __restrict__ hist2,
                                           const unsigned* __restrict__ hist1,
                                           const int* __restrict__ numpos,
                                           unsigned* __restrict__ hist0) {
    const int row = blockIdx.y, tid = threadIdx.x;
    const int np = numpos[row];
    if (np <= 0) return;
    __shared__ int T[256];
    __shared__ Sel r;
    __shared__ int lh[256];
    pick256(ghist + row * 256, want_of(np), tid, T, &r);
    unsigned pfx = (unsigned)r.bin;
    pick256(hist2 + row * 256, r.want, tid, T, &r);
    pfx = (pfx << 8) | (unsigned)r.bin;
    pick256(hist1 + row * 256, r.want, tid, T, &r);
    pfx = (pfx << 8) | (unsigned)r.bin;
    lh[tid] = 0;
    __syncthreads();
    const int i4 = blockIdx.x * 256 + tid;
    if (i4 < K4) {
        const uint4 kv = ((const uint4*)(keys + (size_t)row * K))[i4];
        const unsigned ka[4] = {kv.x, kv.y, kv.z, kv.w};
#pragma unroll
        for (int j = 0; j < 4; j++)
            if ((ka[j] >> 8) == pfx) atomicAdd(&lh[ka[j] & 255u], 1);
    }
    __syncthreads();
    if (lh[tid]) atomicAdd(&hist0[row * 256 + tid], (unsigned)lh[tid]);
}

// ------- TieF: finalize thresh/tieflag; write conf directly for tie rows -----
__global__ __launch_bounds__(1024) void kTieF(const unsigned* __restrict__ keys,
                                              const unsigned* __restrict__ ghist,
                                              const unsigned* __restrict__ hist2,
                                              const unsigned* __restrict__ hist1,
                                              const unsigned* __restrict__ hist0,
                                              const int* __restrict__ numpos,
                                              unsigned* __restrict__ thresh,
                                              unsigned* __restrict__ tieflag,
                                              float* __restrict__ confo) {
    const int row = blockIdx.x, tid = threadIdx.x;
    const int np = numpos[row];
    if (np <= 0) {
        if (tid == 0) { thresh[row] = 0xFFFFFFFFu; tieflag[row] = 0u; }
        return;
    }
    __shared__ int T[256];
    __shared__ Sel r;
    pick256(ghist + row * 256, want_of(np), tid, T, &r);
    unsigned pfx = (unsigned)r.bin;
    pick256(hist2 + row * 256, r.want, tid, T, &r);
    pfx = (pfx << 8) | (unsigned)r.bin;
    pick256(hist1 + row * 256, r.want, tid, T, &r);
    pfx = (pfx << 8) | (unsigned)r.bin;
    pick256(hist0 + row * 256, r.want, tid, T, &r);
    pfx = (pfx << 8) | (unsigned)r.bin;
    const unsigned uT = pfx;
    const int bud = r.want;
    const bool tie = (r.want < r.ceq);
    if (tid == 0) { thresh[row] = uT; tieflag[row] = tie ? 1u : 0u; }
    if (!tie) return;

    // Rare: duplicated threshold key. Rank ties in index order (stable argsort
    // tie-break) and write FINAL conf for this row.
    __shared__ int wsum[16];
    __shared__ int s_run;
    if (tid == 0) s_run = 0;
    __syncthreads();
    const unsigned* kr = keys + (size_t)row * K;
    float* co = confo + (size_t)row * K;
    for (int base = 0; base < K; base += 1024) {
        const int i = base + tid;
        const unsigned key = (i < K) ? kr[i] : 0u;
        const bool eq = (i < K) && (key == uT);
        const unsigned long long bal = __ballot(eq);
        const int lane = tid & 63, wid = tid >> 6;
        if (lane == 0) wsum[wid] = __popcll(bal);
        __syncthreads();
        if (tid == 0) {
            int acc = s_run;
            for (int w = 0; w < 16; w++) { const int t = wsum[w]; wsum[w] = acc; acc += t; }
            s_run = acc;
        }
        __syncthreads();
        if (i < K) {
            const int rank = wsum[wid] + __popcll(bal & ((1ull << lane) - 1ull));
            const bool pos = (key == KEY_NEG1);
            const bool sel = (key > uT) || (eq && rank < bud);
            co[i] = pos ? 1.0f : ((sel && !pos) ? 0.0f : -1.0f);
        }
        __syncthreads();
    }
}

// ---------------- D1: conf_t for non-tie rows --------------------------------
__global__ __launch_bounds__(256) void kD1(const uint4* __restrict__ keys4,
                                           const unsigned* __restrict__ thresh,
                                           const unsigned* __restrict__ tieflag,
                                           float4* __restrict__ confout4) {
    const int t = blockIdx.x * 256 + threadIdx.x;
    if (t >= (BS * K) / 4) return;
    const int row = (t * 4) / K;
    if (tieflag[row]) return;                 // kTieF wrote this row
    const unsigned uT = thresh[row];
    const uint4 kv = keys4[t];
    float rr[4];
    const unsigned ka[4] = {kv.x, kv.y, kv.z, kv.w};
#pragma unroll
    for (int j = 0; j < 4; j++) {
        const unsigned key = ka[j];
        const bool pos = (key == KEY_NEG1);
        const bool sel = (key >= uT);
        rr[j] = pos ? 1.0f : (sel ? 0.0f : -1.0f);
    }
    confout4[t] = make_float4(rr[0], rr[1], rr[2], rr[3]);
}

// ---------------- D2: iw / ow via LDS staging (coalesced stores) --------------
__global__ __launch_bounds__(256) void kD2(const float* __restrict__ confv,
                                           const int* __restrict__ numpos,
                                           float* __restrict__ iw,
                                           float* __restrict__ ow) {
    const int tid = threadIdx.x;
    const int g0 = blockIdx.x * 256;
    const int g = g0 + tid;                   // global prior index (exact grid)
    __shared__ float si[1280];
    __shared__ float so2[1280];
    const float c = confv[g];
    const int row = g / K;
    const float inv = 1.0f / (float)((numpos[row] * 4) | 1);
    const float iwv = (c == 1.0f) ? 1.0f : 0.0f;
    const float owv = (c >= 0.0f) ? inv : 0.0f;
#pragma unroll
    for (int j = 0; j < 5; j++) { si[tid * 5 + j] = iwv; so2[tid * 5 + j] = owv; }
    __syncthreads();
    const size_t e0 = (size_t)g0 * 5;
#pragma unroll
    for (int j = 0; j < 5; j++) {
        const int s = j * 256 + tid;
        iw[e0 + s] = si[s];
        ow[e0 + s] = so2[s];
    }
}

extern "C" void kernel_launch(void* const* d_in, const int* in_sizes, int n_in,
                              void* d_out, int out_size, void* d_ws, size_t ws_size,
                              hipStream_t stream) {
    const float* conf   = (const float*)d_in[0];
    const float* gt     = (const float*)d_in[1];
    const float* priors = (const float*)d_in[2];

    float* out   = (float*)d_out;
    float* loc_t = out;
    float* confo = out + 8000000;
    float* iw    = out + 9600000;
    float* ow    = out + 17600000;

    // Scratch inside ow region (fully rewritten by kD2 last):
    unsigned* owu   = (unsigned*)ow;
    unsigned* keys  = owu;                    // 1,600,000 u32
    unsigned* ghist = owu + 1600000;          // 8192
    unsigned* hist2 = owu + 1608192;          // 8192
    unsigned* hist1 = owu + 1616384;          // 8192
    unsigned* hist0 = owu + 1624576;          // 8192
    // Per-row scalars in d_ws:
    int*      numpos  = (int*)d_ws;           // 32
    unsigned* thresh  = (unsigned*)d_ws + 32;  // 32
    unsigned* tieflag = (unsigned*)d_ws + 64;  // 32

    hipMemsetAsync(numpos, 0, 32 * sizeof(int), stream);
    hipMemsetAsync(ghist, 0, 4 * 8192 * sizeof(unsigned), stream);

    dim3 gA((K + 255) / 256, BS);
    dim3 gP(NCH, BS);
    kA<<<gA, 256, 0, stream>>>(conf, gt, priors, loc_t, keys, ghist, numpos);
    kH2<<<gP, 256, 0, stream>>>(keys, ghist, numpos, hist2);
    kH1<<<gP, 256, 0, stream>>>(keys, ghist, hist2, numpos, hist1);
    kH0<<<gP, 256, 0, stream>>>(keys, ghist, hist2, hist1, numpos, hist0);
    kTieF<<<BS, 1024, 0, stream>>>(keys, ghist, hist2, hist1, hist0, numpos,
                                   thresh, tieflag, confo);
    kD1<<<((BS * K) / 4 + 255) / 256, 256, 0, stream>>>((const uint4*)keys,
                                                        thresh, tieflag,
                                                        (float4*)confo);
    kD2<<<(BS * K) / 256, 256, 0, stream>>>(confo, numpos, iw, ow);
}

// Round 5
// 114.203 us; speedup vs baseline: 2.4458x; 1.0830x over previous
//
#include <hip/hip_runtime.h>
#include <cstdint>

#define BS 32
#define K 50000
#define K4 12500                 // K/4 uint4 per row
#define NCH 49                   // ceil(K4/256) == ceil(K/1024)
#define NGT 32
#define KROW (K * 5)
#define KEY_NEG1 0x407FFFFFu     // f2key(-1.0f)

__device__ __forceinline__ unsigned f2key(float f) {
    unsigned b = __float_as_uint(f);
    return (b & 0x80000000u) ? ~b : (b | 0x80000000u);
}

struct Sel { int bin; int want; int ceq; };

// Block-parallel pick: highest bin with from-top cumulative >= want.
__device__ __forceinline__ void pick256(const unsigned* __restrict__ hist_row,
                                        int want, int tid, int* T, Sel* r) {
    int h = 0;
    if (tid < 256) { h = (int)hist_row[tid]; T[tid] = h; }
    __syncthreads();
#pragma unroll
    for (int o = 1; o < 256; o <<= 1) {
        int add = 0;
        if (tid < 256) add = (tid + o < 256) ? T[tid + o] : 0;
        __syncthreads();
        if (tid < 256) T[tid] += add;
        __syncthreads();
    }
    if (tid < 256) {
        const int Ti = T[tid];
        const int Tn = (tid == 255) ? (want - 1) : T[tid + 1];
        if (Ti >= want && Tn < want) { r->bin = tid; r->ceq = h; r->want = want - (Ti - h); }
    }
    __syncthreads();
}

__device__ __forceinline__ int want_of(int np) {
    const long long w0 = 3LL * (long long)np;
    return (w0 > K) ? K : (int)w0;
}

// ------ Kernel A: 4 priors/thread, branchless match, loc_t, keys, hist ------
__global__ __launch_bounds__(256) void kA(const float* __restrict__ conf,
                                          const float* __restrict__ gt,
                                          const float* __restrict__ priors,
                                          float* __restrict__ loc_t,
                                          unsigned* __restrict__ keys,
                                          unsigned* __restrict__ ghist,
                                          int* __restrict__ numpos) {
    const int b    = blockIdx.y;
    const int tid  = threadIdx.x;
    const int k0   = blockIdx.x * 1024;
    const int lane = tid & 63;

    __shared__ float sb[5120];          // priors staging, reused for loc_t out
    __shared__ int   lh[256];
    __shared__ int   lpos;

    lh[tid] = 0;
    if (tid == 0) lpos = 0;

    const int ebase = k0 * 5;
    const float* prow = priors + (size_t)b * KROW;
#pragma unroll
    for (int j = 0; j < 20; j++) {
        const int e = j * 256 + tid;
        if (ebase + e < KROW) sb[e] = prow[ebase + e];
    }
    __syncthreads();

    float px[4], py[4], pw[4], ph[4], pa[4];
#pragma unroll
    for (int c = 0; c < 4; c++) {
        const int l = (c * 256 + tid) * 5;   // stride-5 LDS: 2-way alias = free
        px[c] = sb[l];     py[c] = sb[l + 1]; pw[c] = sb[l + 2];
        ph[c] = sb[l + 3]; pa[c] = sb[l + 4];
    }
    __syncthreads();                    // sb free for reuse after this

    float fcnt[4] = {0.f, 0.f, 0.f, 0.f};
    float sx[4] = {0.f,0.f,0.f,0.f}, sy[4] = {0.f,0.f,0.f,0.f},
          sw[4] = {0.f,0.f,0.f,0.f}, sh[4] = {0.f,0.f,0.f,0.f},
          sa[4] = {0.f,0.f,0.f,0.f};

    const unsigned* gtu = (const unsigned*)(gt + (size_t)b * NGT * 5);
#pragma unroll
    for (int n = 0; n < NGT; n++) {
        const unsigned ux = gtu[n * 5],     uy = gtu[n * 5 + 1],
                       uw = gtu[n * 5 + 2], uh = gtu[n * 5 + 3],
                       ua = gtu[n * 5 + 4];
        const bool gvalid = ((ux | uy | uw | uh | ua) != 0u);
        const float gx  = gvalid ? __uint_as_float(ux) : 1e30f; // poison: no match
        const float gy  = __uint_as_float(uy);
        const float gww = __uint_as_float(uw);
        const float ghh = __uint_as_float(uh);
        const float ga  = __uint_as_float(ua);
#pragma unroll
        for (int c = 0; c < 4; c++) {
            const bool m = (fabsf(px[c] - gx) <= 16.f) &
                           (fabsf(py[c] - gy) <= 16.f) &
                           (fabsf(pa[c] - ga) <= 15.f);
            const float mf = m ? 1.0f : 0.0f;
            fcnt[c] += mf;
            sx[c] = fmaf(mf, gx,  sx[c]);
            sy[c] = fmaf(mf, gy,  sy[c]);
            sw[c] = fmaf(mf, gww, sw[c]);
            sh[c] = fmaf(mf, ghh, sh[c]);
            sa[c] = fmaf(mf, ga,  sa[c]);
        }
    }

    const float2* c2p = (const float2*)(conf + (size_t)b * K * 2);
    unsigned key[4] = {0u, 0u, 0u, 0u};
    bool     vk[4];
#pragma unroll
    for (int c = 0; c < 4; c++) {
        const int k = k0 + c * 256 + tid;
        vk[c] = (k < K);
        const float inv = 1.0f / fmaxf(fcnt[c], 1.0f);   // cnt==0 -> 1 (exact)
        const float rpw = 1.0f / pw[c], rph = 1.0f / ph[c];
        const float lx  = (sx[c] + 1e-14f) * inv;
        const float ly  = (sy[c] + 1e-14f) * inv;
        const float lw  = (sw[c] + 1e-14f) * inv;
        const float lh2 = (sh[c] + 1e-14f) * inv;
        const float la  = (sa[c] + 1e-14f) * inv;
        const int l = (c * 256 + tid) * 5;
        sb[l]     = (lx - px[c]) * rpw * (1.0f / 0.1f);
        sb[l + 1] = (ly - py[c]) * rph * (1.0f / 0.1f);
        sb[l + 2] = __logf(lw * rpw) * (1.0f / 0.2f);
        sb[l + 3] = __logf(lh2 * rph) * (1.0f / 0.2f);
        sb[l + 4] = (la - pa[c]) * (1.0f / 0.1f);
        if (vk[c]) {
            const float2 cc = c2p[k];
            const float mm = fmaxf(cc.x, cc.y);
            const float lse = mm + __logf(__expf(cc.x - mm) + __expf(cc.y - mm));
            const float loss = (fcnt[c] > 0.f) ? -1.0f : (lse - cc.x);
            key[c] = f2key(loss);
            keys[(size_t)b * K + k] = key[c];
        }
    }

    // wave-aggregated histogram + pos count
#pragma unroll
    for (int c = 0; c < 4; c++) {
        const unsigned bin = key[c] >> 24;
        bool todo = vk[c];
        while (__any(todo)) {
            const unsigned long long act = __ballot(todo);
            const int leader = __ffsll(act) - 1;
            const unsigned lbin = __shfl(bin, leader);
            const bool mine = todo && (bin == lbin);
            const unsigned long long grp = __ballot(mine);
            if (lane == leader) atomicAdd(&lh[lbin], (int)__popcll(grp));
            todo = todo && !mine;
        }
        const unsigned long long pm = __ballot(vk[c] && (fcnt[c] > 0.f));
        if (lane == 0 && pm) atomicAdd(&lpos, (int)__popcll(pm));
    }
    __syncthreads();

#pragma unroll
    for (int j = 0; j < 20; j++) {
        const int e = j * 256 + tid;
        if (ebase + e < KROW) loc_t[(size_t)b * KROW + ebase + e] = sb[e];
    }
    const int h = lh[tid];
    if (h) atomicAdd(&ghist[b * 256 + tid], (unsigned)h);
    if (tid == 0 && lpos) atomicAdd(&numpos[b], lpos);
}

// ---------------- H2/H1/H0: conditioned byte histograms ----------------------
__global__ __launch_bounds__(256) void kH2(const unsigned* __restrict__ keys,
                                           const unsigned* __restrict__ ghist,
                                           const int* __restrict__ numpos,
                                           unsigned* __restrict__ hist2) {
    const int row = blockIdx.y, tid = threadIdx.x;
    const int np = numpos[row];
    if (np <= 0) return;
    __shared__ int T[256];
    __shared__ Sel r;
    __shared__ int lh[256];
    pick256(ghist + row * 256, want_of(np), tid, T, &r);
    const int b3 = r.bin;
    lh[tid] = 0;
    __syncthreads();
    const int i4 = blockIdx.x * 256 + tid;
    if (i4 < K4) {
        const uint4 kv = ((const uint4*)(keys + (size_t)row * K))[i4];
        const unsigned ka[4] = {kv.x, kv.y, kv.z, kv.w};
#pragma unroll
        for (int j = 0; j < 4; j++)
            if ((int)(ka[j] >> 24) == b3) atomicAdd(&lh[(ka[j] >> 16) & 255u], 1);
    }
    __syncthreads();
    if (lh[tid]) atomicAdd(&hist2[row * 256 + tid], (unsigned)lh[tid]);
}

__global__ __launch_bounds__(256) void kH1(const unsigned* __restrict__ keys,
                                           const unsigned* __restrict__ ghist,
                                           const unsigned* __restrict__ hist2,
                                           const int* __restrict__ numpos,
                                           unsigned* __restrict__ hist1) {
    const int row = blockIdx.y, tid = threadIdx.x;
    const int np = numpos[row];
    if (np <= 0) return;
    __shared__ int T[256];
    __shared__ Sel r;
    __shared__ int lh[256];
    pick256(ghist + row * 256, want_of(np), tid, T, &r);
    const unsigned b3 = (unsigned)r.bin;
    pick256(hist2 + row * 256, r.want, tid, T, &r);
    const unsigned p16 = (b3 << 8) | (unsigned)r.bin;
    lh[tid] = 0;
    __syncthreads();
    const int i4 = blockIdx.x * 256 + tid;
    if (i4 < K4) {
        const uint4 kv = ((const uint4*)(keys + (size_t)row * K))[i4];
        const unsigned ka[4] = {kv.x, kv.y, kv.z, kv.w};
#pragma unroll
        for (int j = 0; j < 4; j++)
            if ((ka[j] >> 16) == p16) atomicAdd(&lh[(ka[j] >> 8) & 255u], 1);
    }
    __syncthreads();
    if (lh[tid]) atomicAdd(&hist1[row * 256 + tid], (unsigned)lh[tid]);
}

__global__ __launch_bounds__(256) void kH0(const unsigned* __restrict__ keys,
                                           const unsigned* __restrict__ ghist,
                                           const unsigned* __restrict__ hist2,
                                           const unsigned* __restrict__ hist1,
                                           const int* __restrict__ numpos,
                                           unsigned* __restrict__ hist0) {
    const int row = blockIdx.y, tid = threadIdx.x;
    const int np = numpos[row];
    if (np <= 0) return;
    __shared__ int T[256];
    __shared__ Sel r;
    __shared__ int lh[256];
    pick256(ghist + row * 256, want_of(np), tid, T, &r);
    unsigned pfx = (unsigned)r.bin;
    pick256(hist2 + row * 256, r.want, tid, T, &r);
    pfx = (pfx << 8) | (unsigned)r.bin;
    pick256(hist1 + row * 256, r.want, tid, T, &r);
    pfx = (pfx << 8) | (unsigned)r.bin;
    lh[tid] = 0;
    __syncthreads();
    const int i4 = blockIdx.x * 256 + tid;
    if (i4 < K4) {
        const uint4 kv = ((const uint4*)(keys + (size_t)row * K))[i4];
        const unsigned ka[4] = {kv.x, kv.y, kv.z, kv.w};
#pragma unroll
        for (int j = 0; j < 4; j++)
            if ((ka[j] >> 8) == pfx) atomicAdd(&lh[ka[j] & 255u], 1);
    }
    __syncthreads();
    if (lh[tid]) atomicAdd(&hist0[row * 256 + tid], (unsigned)lh[tid]);
}

// ------- TieF: finalize thresh/tieflag; write final conf for tie rows --------
__global__ __launch_bounds__(1024) void kTieF(const unsigned* __restrict__ keys,
                                              const unsigned* __restrict__ ghist,
                                              const unsigned* __restrict__ hist2,
                                              const unsigned* __restrict__ hist1,
                                              const unsigned* __restrict__ hist0,
                                              const int* __restrict__ numpos,
                                              unsigned* __restrict__ thresh,
                                              unsigned* __restrict__ tieflag,
                                              float* __restrict__ confo) {
    const int row = blockIdx.x, tid = threadIdx.x;
    const int np = numpos[row];
    if (np <= 0) {
        if (tid == 0) { thresh[row] = 0xFFFFFFFFu; tieflag[row] = 0u; }
        return;
    }
    __shared__ int T[256];
    __shared__ Sel r;
    pick256(ghist + row * 256, want_of(np), tid, T, &r);
    unsigned pfx = (unsigned)r.bin;
    pick256(hist2 + row * 256, r.want, tid, T, &r);
    pfx = (pfx << 8) | (unsigned)r.bin;
    pick256(hist1 + row * 256, r.want, tid, T, &r);
    pfx = (pfx << 8) | (unsigned)r.bin;
    pick256(hist0 + row * 256, r.want, tid, T, &r);
    pfx = (pfx << 8) | (unsigned)r.bin;
    const unsigned uT = pfx;
    const int bud = r.want;
    const bool tie = (r.want < r.ceq);
    if (tid == 0) { thresh[row] = uT; tieflag[row] = tie ? 1u : 0u; }
    if (!tie) return;

    // Rare: duplicated threshold key — rank ties in index order, write conf.
    __shared__ int wsum[16];
    __shared__ int s_run;
    if (tid == 0) s_run = 0;
    __syncthreads();
    const unsigned* kr = keys + (size_t)row * K;
    float* co = confo + (size_t)row * K;     // same region as keys: RAW per i
    for (int base = 0; base < K; base += 1024) {
        const int i = base + tid;
        const unsigned key = (i < K) ? kr[i] : 0u;
        const bool eq = (i < K) && (key == uT);
        const unsigned long long bal = __ballot(eq);
        const int lane = tid & 63, wid = tid >> 6;
        if (lane == 0) wsum[wid] = __popcll(bal);
        __syncthreads();
        if (tid == 0) {
            int acc = s_run;
            for (int w = 0; w < 16; w++) { const int t = wsum[w]; wsum[w] = acc; acc += t; }
            s_run = acc;
        }
        __syncthreads();
        if (i < K) {
            const int rank = wsum[wid] + __popcll(bal & ((1ull << lane) - 1ull));
            const bool pos = (key == KEY_NEG1);
            const bool sel = (key > uT) || (eq && rank < bud);
            co[i] = pos ? 1.0f : ((sel && !pos) ? 0.0f : -1.0f);
        }
        __syncthreads();
    }
}

// ------- D12: conf (non-tie) + iw/ow, LDS-staged coalesced stores ------------
__global__ __launch_bounds__(256) void kD12(const unsigned* __restrict__ keys,
                                            const unsigned* __restrict__ thresh,
                                            const unsigned* __restrict__ tieflag,
                                            const int* __restrict__ numpos,
                                            float* __restrict__ confo,
                                            float* __restrict__ iw,
                                            float* __restrict__ ow) {
    const int tid = threadIdx.x;
    const int g0 = blockIdx.x * 256;
    const int g = g0 + tid;                  // exact grid: no bound check
    __shared__ float si[1280];
    __shared__ float so2[1280];
    const int row = g / K;
    const unsigned key = keys[g];            // keys live in conf region
    float c;
    if (tieflag[row]) {
        c = __uint_as_float(key);            // kTieF already wrote final conf
    } else {
        const unsigned uT = thresh[row];
        const bool pos = (key == KEY_NEG1);
        c = pos ? 1.0f : ((key >= uT) ? 0.0f : -1.0f);
        confo[g] = c;                        // overwrite key slot with conf
    }
    const float inv = 1.0f / (float)((numpos[row] * 4) | 1);
    const float iwv = (c == 1.0f) ? 1.0f : 0.0f;
    const float owv = (c >= 0.0f) ? inv : 0.0f;
#pragma unroll
    for (int j = 0; j < 5; j++) { si[tid * 5 + j] = iwv; so2[tid * 5 + j] = owv; }
    __syncthreads();
    const size_t e0 = (size_t)g0 * 5;
#pragma unroll
    for (int j = 0; j < 5; j++) {
        const int s = j * 256 + tid;
        iw[e0 + s] = si[s];
        ow[e0 + s] = so2[s];
    }
}

extern "C" void kernel_launch(void* const* d_in, const int* in_sizes, int n_in,
                              void* d_out, int out_size, void* d_ws, size_t ws_size,
                              hipStream_t stream) {
    const float* conf   = (const float*)d_in[0];
    const float* gt     = (const float*)d_in[1];
    const float* priors = (const float*)d_in[2];

    float* out   = (float*)d_out;
    float* loc_t = out;
    float* confo = out + 8000000;
    float* iw    = out + 9600000;
    float* ow    = out + 17600000;

    // keys live IN the conf region (same size); overwritten with conf last.
    unsigned* keys  = (unsigned*)confo;
    // hists live at the start of the ow region (clobbered only by kD12).
    unsigned* owu   = (unsigned*)ow;
    unsigned* ghist = owu;                    // 8192
    unsigned* hist2 = owu + 8192;             // 8192
    unsigned* hist1 = owu + 16384;            // 8192
    unsigned* hist0 = owu + 24576;            // 8192
    // Per-row scalars in d_ws:
    int*      numpos  = (int*)d_ws;            // 32
    unsigned* thresh  = (unsigned*)d_ws + 32;  // 32
    unsigned* tieflag = (unsigned*)d_ws + 64;  // 32

    hipMemsetAsync(numpos, 0, 3 * 32 * sizeof(int), stream);
    hipMemsetAsync(ghist, 0, 4 * 8192 * sizeof(unsigned), stream);

    dim3 gA(49, BS);                          // 49*1024 >= K priors per row
    dim3 gP(NCH, BS);
    kA<<<gA, 256, 0, stream>>>(conf, gt, priors, loc_t, keys, ghist, numpos);
    kH2<<<gP, 256, 0, stream>>>(keys, ghist, numpos, hist2);
    kH1<<<gP, 256, 0, stream>>>(keys, ghist, hist2, numpos, hist1);
    kH0<<<gP, 256, 0, stream>>>(keys, ghist, hist2, hist1, numpos, hist0);
    kTieF<<<BS, 1024, 0, stream>>>(keys, ghist, hist2, hist1, hist0, numpos,
                                   thresh, tieflag, confo);
    kD12<<<(BS * K) / 256, 256, 0, stream>>>(keys, thresh, tieflag, numpos,
                                             confo, iw, ow);
}